// Round 18
// baseline (600.578 us; speedup 1.0000x reference)
//
#include <hip/hip_runtime.h>
#include <math.h>

// SpiralNet v16: fused single kernel with SOFTWARE grid barrier.
// v15 failed because hipLaunchCooperativeKernel is not graph-capturable
// (absmax 7.625 = max|ref| -> kernel never ran, output stayed zero).
// v16 = same fused body (exact v10 bf16 math, absmax 0.031 known-safe),
// plain launch + hand-rolled 2-level sense-reversing barrier:
//  - 49 groups x 16 blocks; group counters cacheline-strided (v13 lesson:
//    782 RMWs on one line ~ 30us; tree -> ~3-4us/barrier).
//  - agent-scope atomic loads for spin; s_sleep(2) backoff; ALL spins
//    bounded (~50ms) -> malfunction = finite absmax fail, never a hang.
//  - residency guaranteed: grid 782 <= 4 blk/CU (launch_bounds(256,4),
//    VGPR cap 128) x 256 CU = 1024; LDS 24KB -> 6/CU.
//  - barrier state in d_ws, re-zeroed per replay by captured memsetAsync.
// Boundary theory (v14: +2 kernels/+2 boundaries = +26us -> ~10us each):
// predict 158 -> ~130-142us; ~155+ refutes. absmax 0.03125.
// [Rounds 15-17: resubmitted unchanged — GPU broker timeouts, no data.]

typedef __bf16 bf16;
typedef bf16  bf16x4 __attribute__((ext_vector_type(4)));
typedef bf16  bf16x8 __attribute__((ext_vector_type(8)));
typedef float f32x4  __attribute__((ext_vector_type(4)));

__device__ __forceinline__ int aload(int* p) {
    return __hip_atomic_load(p, __ATOMIC_ACQUIRE, __HIP_MEMORY_SCOPE_AGENT);
}
__device__ __forceinline__ void astore(int* p, int v) {
    __hip_atomic_store(p, v, __ATOMIC_RELEASE, __HIP_MEMORY_SCOPE_AGENT);
}

// Two-level grid barrier. bar layout (ints, 32-int = 128B stride):
// [0..63]*32 group counters | [64..127]*32 group gens | 128*32 root cnt |
// 128*32+32 root gen. All zeroed before launch.
__device__ __forceinline__ void gbar(int* bar, int nblk) {
    __syncthreads();
    if (threadIdx.x == 0) {
        __threadfence();                       // release data
        const int grp  = blockIdx.x >> 4;
        const int ngrp = (nblk + 15) >> 4;
        const int gsz  = min(16, nblk - (grp << 4));
        int* gcnt = bar + grp * 32;
        int* ggen = bar + 64 * 32 + grp * 32;
        int* rcnt = bar + 128 * 32;
        int* rgen = bar + 128 * 32 + 32;
        const int g = aload(ggen);
        if (atomicAdd(gcnt, 1) == gsz - 1) {   // last in group
            astore(gcnt, 0);
            const int rg = aload(rgen);
            if (atomicAdd(rcnt, 1) == ngrp - 1) {  // last group
                astore(rcnt, 0);
                __hip_atomic_fetch_add(rgen, 1, __ATOMIC_RELEASE,
                                       __HIP_MEMORY_SCOPE_AGENT);
            } else {
                int guard = 0;
                while (aload(rgen) == rg && ++guard < (1 << 22))
                    __builtin_amdgcn_s_sleep(2);
            }
            __hip_atomic_fetch_add(ggen, 1, __ATOMIC_RELEASE,
                                   __HIP_MEMORY_SCOPE_AGENT);
        } else {
            int guard = 0;
            while (aload(ggen) == g && ++guard < (1 << 22))
                __builtin_amdgcn_s_sleep(2);
        }
        __threadfence();                       // acquire side
    }
    __syncthreads();
}

// Pack W [K][COUT] f32 into fragment-ordered bf16 (v10 layout).
template<int CIN, int COUT>
__device__ __forceinline__ void pack_one(const float* __restrict__ W,
                                         bf16* __restrict__ BP, int e) {
    constexpr int NT = COUT / 16, CC = CIN / 32;
    const int f = e >> 9, r = e & 511, lane = r >> 3, j = r & 7;
    const int t = f % NT, cc = (f / NT) % CC, s = f / (NT * CC);
    const int col = t * 16 + (lane & 15);
    const int k   = s * CIN + cc * 32 + (lane >> 4) * 8 + j;
    BP[e] = (bf16)W[k * COUT + col];
}

// One spiral layer over all tiles (grid-stride). Exact v10 per-tile body.
template<int CIN, int COUT, bool ELU, bool NTS, typename TOUT>
__device__ __forceinline__ void layer_phase(
    const bf16* __restrict__ h, const int* __restrict__ idx,
    const bf16* __restrict__ BP, const float* __restrict__ bias,
    TOUT* __restrict__ out, bf16* Bs, int n, int ntiles)
{
    constexpr int CC  = CIN / 32;
    constexpr int NT  = COUT / 16;
    constexpr int PS  = CIN * COUT;
    constexpr int SC  = 6 / CC;
    constexpr int NCH = 12 / SC;
    constexpr int PL  = 6;

    const int tid  = threadIdx.x;
    const int lane = tid & 63;
    const int wave = tid >> 6;
    const int m    = lane & 15;
    const int quad = lane >> 4;

    for (int tile = blockIdx.x; tile < ntiles; tile += gridDim.x) {
        const int i0 = (tile * 4 + wave) * 16;
        const bool valid = (i0 < n);

        const int ir = min(i0 + m, n - 1);
        const int4* ip = reinterpret_cast<const int4*>(idx + (size_t)ir * 12);
        const int4 q0 = ip[0], q1 = ip[1], q2 = ip[2];
        const int rg[12] = {q0.x,q0.y,q0.z,q0.w, q1.x,q1.y,q1.z,q1.w,
                            q2.x,q2.y,q2.z,q2.w};

        f32x4 acc[NT] = {};

        #pragma unroll
        for (int c = 0; c < NCH; ++c) {
            __syncthreads();             // Bs reuse (prev chunk/tile/phase)
            const bf16* src = BP + (size_t)c * SC * PS;
            #pragma unroll
            for (int r2 = tid; r2 < SC * PS / 8; r2 += 256)
                *reinterpret_cast<bf16x8*>(&Bs[r2 * 8]) =
                    *reinterpret_cast<const bf16x8*>(&src[r2 * 8]);
            __syncthreads();

            bf16x8 a[PL];
            #pragma unroll
            for (int sl = 0; sl < SC; ++sl)
                #pragma unroll
                for (int cc = 0; cc < CC; ++cc)
                    a[sl * CC + cc] = *reinterpret_cast<const bf16x8*>(
                        h + (size_t)rg[c * SC + sl] * CIN + cc * 32 + quad * 8);
            __builtin_amdgcn_sched_barrier(0);
            #pragma unroll
            for (int p = 0; p < PL; ++p)
                #pragma unroll
                for (int t = 0; t < NT; ++t) {
                    const bf16x8 b = *reinterpret_cast<const bf16x8*>(
                        &Bs[(p * NT + t) * 512 + lane * 8]);
                    acc[t] = __builtin_amdgcn_mfma_f32_16x16x32_bf16(
                        a[p], b, acc[t], 0, 0, 0);
                }
        }

        if (valid) {
            #pragma unroll
            for (int t = 0; t < NT; ++t) {
                const int col = t * 16 + m;
                const float bv = bias[col];
                #pragma unroll
                for (int g = 0; g < 4; ++g) {
                    const int row = i0 + quad * 4 + g;
                    float v = acc[t][g] + bv;
                    if (ELU) v = (v > 0.f) ? v : (__expf(v) - 1.f);
                    if (NTS) __builtin_nontemporal_store(
                                 (TOUT)v, out + (size_t)row * COUT + col);
                    else     out[(size_t)row * COUT + col] = (TOUT)v;
                }
            }
        }
    }
}

__global__ __launch_bounds__(256, 4)
void fused(const float* __restrict__ x, const int* __restrict__ idx,
           const float* __restrict__ W0, const float* __restrict__ b0,
           const float* __restrict__ W1, const float* __restrict__ b1,
           const float* __restrict__ W2, const float* __restrict__ b2,
           float* __restrict__ out, bf16* __restrict__ xb,
           bf16* __restrict__ h1, bf16* __restrict__ h2,
           bf16* __restrict__ B0, bf16* __restrict__ B1,
           bf16* __restrict__ B2, int* __restrict__ bar, int n)
{
    __shared__ bf16 Bs[12288];           // 24 KB, reused by all phases

    const int G   = gridDim.x * 256;
    const int gt  = blockIdx.x * 256 + threadIdx.x;
    const int nblk = gridDim.x;
    const int ntiles = (n + 63) / 64;

    // ---- Phase P: x -> bf16 table + weight fragment packing ----
    for (int u = gt; u < n * 8; u += G) {
        const int e = u * 4;
        const f32x4 v = *reinterpret_cast<const f32x4*>(x + e);
        bf16x4 o = {(bf16)v[0], (bf16)v[1], (bf16)v[2], (bf16)v[3]};
        *reinterpret_cast<bf16x4*>(xb + e) = o;
    }
    if (gt < 24576)                       pack_one<32, 64>(W0, B0, gt);
    else if (gt < 24576 + 49152)          pack_one<64, 64>(W1, B1, gt - 24576);
    else if (gt < 24576 + 49152 + 24576)  pack_one<64, 32>(W2, B2, gt - 24576 - 49152);

    gbar(bar, nblk);

    // ---- Phase 0: L0 (32 -> 64, ELU) ----
    layer_phase<32, 64, true,  false, bf16 >(xb, idx, B0, b0, h1, Bs, n, ntiles);
    gbar(bar, nblk);

    // ---- Phase 1: L1 (64 -> 64, ELU) ----
    layer_phase<64, 64, true,  false, bf16 >(h1, idx, B1, b1, h2, Bs, n, ntiles);
    gbar(bar, nblk);

    // ---- Phase 2: L2 (64 -> 32, no act, fp32 nt out) ----
    layer_phase<64, 32, false, true,  float>(h2, idx, B2, b2, out, Bs, n, ntiles);
}

extern "C" void kernel_launch(void* const* d_in, const int* in_sizes, int n_in,
                              void* d_out, int out_size, void* d_ws, size_t ws_size,
                              hipStream_t stream) {
    const float* x   = (const float*)d_in[0];   // [N,32] fp32
    const int*   idx = (const int*)d_in[1];     // [N,12]
    const float* W0  = (const float*)d_in[2];   // [384,64]
    const float* b0  = (const float*)d_in[3];
    const float* W1  = (const float*)d_in[4];   // [768,64]
    const float* b1  = (const float*)d_in[5];
    const float* W2  = (const float*)d_in[6];   // [768,32]
    const float* b2  = (const float*)d_in[7];
    float* out = (float*)d_out;                 // [N,32] fp32

    const int n = in_sizes[0] / 32;             // N = 100000

    bf16* xb = (bf16*)d_ws;                     // [n,32]
    bf16* h1 = xb + (size_t)n * 32;             // [n,64]
    bf16* h2 = h1 + (size_t)n * 64;             // [n,64]
    bf16* B0 = h2 + (size_t)n * 64;             // 384*64
    bf16* B1 = B0 + 384 * 64;                   // 768*64
    bf16* B2 = B1 + 768 * 64;                   // 768*32

    // Barrier state after tables, 4 KB aligned; zeroed per replay (captured).
    const size_t tbl_bytes = ((size_t)n * 160 + 98304) * sizeof(bf16);
    const size_t bar_off   = (tbl_bytes + 4095) & ~(size_t)4095;
    int* bar = (int*)((char*)d_ws + bar_off);
    const size_t bar_bytes = (size_t)(128 * 32 + 64) * sizeof(int); // ~16.6KB

    const int ntiles = (n + 63) / 64;           // 1563
    const int grid   = (ntiles + 1) / 2;        // 782 <= 1024 resident

    hipMemsetAsync(bar, 0, bar_bytes, stream);

    fused<<<grid, dim3(256), 0, stream>>>(
        x, idx, W0, b0, W1, b1, W2, b2, out,
        xb, h1, h2, B0, B1, B2, bar, n);
}